// Round 4
// baseline (745.027 us; speedup 1.0000x reference)
//
#include <hip/hip_runtime.h>
#include <math.h>

#define B_ 4
#define S_ 2048
#define D_ 512
#define H_ 8
#define NEG_FILL (-1e-9f)

typedef __attribute__((ext_vector_type(8))) short bf16x8;
typedef __attribute__((ext_vector_type(4))) float f32x4;

#define MFMA16(A, Bm, C) __builtin_amdgcn_mfma_f32_16x16x32_bf16((A), (Bm), (C), 0, 0, 0)

__device__ __forceinline__ short f2b(float f) {
  union { float f; unsigned u; } x;
  x.f = f;
  unsigned r = x.u + 0x7fffu + ((x.u >> 16) & 1u);
  return (short)(r >> 16);
}

// ---------------------------------------------------------------------------
// prep: W[512x512] fp32 (k-major) -> Wt[n][k] bf16 (transposed), z picks matrix
// ---------------------------------------------------------------------------
__global__ __launch_bounds__(256) void prep_wt(
    const float* __restrict__ Wq, const float* __restrict__ Wk,
    const float* __restrict__ Wv, const float* __restrict__ Wo,
    short* __restrict__ Wqt, short* __restrict__ Wkt,
    short* __restrict__ Wvt, short* __restrict__ Wot)
{
  const float* W; short* Wt;
  switch (blockIdx.z) {
    case 0: W = Wq; Wt = Wqt; break;
    case 1: W = Wk; Wt = Wkt; break;
    case 2: W = Wv; Wt = Wvt; break;
    default: W = Wo; Wt = Wot; break;
  }
  __shared__ float Ws[64 * 68];
  const int t = threadIdx.x;
  const int n0 = blockIdx.x * 64, k0 = blockIdx.y * 64;

  #pragma unroll
  for (int rep = 0; rep < 4; ++rep) {
    int e4 = rep * 256 + t;           // float4 units
    int r = e4 >> 4, c0 = (e4 & 15) * 4;
    *(float4*)&Ws[r * 68 + c0] = *(const float4*)&W[(size_t)(k0 + r) * 512 + n0 + c0];
  }
  __syncthreads();

  int rn = t >> 2;                    // out row (n)
  int kb = (t & 3) * 16;              // out col base (k)
  union { short s[8]; int4 v; } pk;
  #pragma unroll
  for (int half = 0; half < 2; ++half) {
    #pragma unroll
    for (int i = 0; i < 8; ++i)
      pk.s[i] = f2b(Ws[(kb + half * 8 + i) * 68 + rn]);
    *(int4*)&Wt[(size_t)(n0 + rn) * 512 + k0 + kb + half * 8] = pk.v;
  }
}

// ---------------------------------------------------------------------------
// QKV projection, MFMA bf16, 128x128 tile (m93 structure), BK=64.
// 4 waves in 2x2; each wave computes a 64x64 sub-tile = 4x4 16x16 frags.
// z=0 -> qh[bh][s][64], z=1 -> kh[bh][s][64], z=2 -> vt[bh][d][2048]
// ---------------------------------------------------------------------------
__global__ __launch_bounds__(256) void qkv_mfma(
    const float* __restrict__ q, const float* __restrict__ k, const float* __restrict__ v,
    const short* __restrict__ Wqt, const short* __restrict__ Wkt, const short* __restrict__ Wvt,
    short* __restrict__ qh, short* __restrict__ kh, short* __restrict__ vt)
{
  const int z = blockIdx.z;
  const float* X = (z == 0) ? q : (z == 1) ? k : v;
  const short* Wt = (z == 0) ? Wqt : (z == 1) ? Wkt : Wvt;

  __shared__ short Xs[128 * 72];
  __shared__ short Wsh[128 * 72];

  const int t = threadIdx.x;
  const int wave = t >> 6, lane = t & 63, quad = lane >> 4, l15 = lane & 15;
  const int wm = wave >> 1, wn = wave & 1;
  const int tile_n = blockIdx.x * 128;
  const int tile_m = blockIdx.y * 128;

  f32x4 acc[4][4];
  #pragma unroll
  for (int mt = 0; mt < 4; ++mt)
    #pragma unroll
    for (int nt = 0; nt < 4; ++nt) acc[mt][nt] = (f32x4){0.f, 0.f, 0.f, 0.f};

  for (int k0 = 0; k0 < 512; k0 += 64) {
    __syncthreads();
    #pragma unroll
    for (int rep = 0; rep < 8; ++rep) {
      int e4 = rep * 256 + t;
      int row = e4 >> 4, c0 = (e4 & 15) * 4;
      float4 xv = *(const float4*)&X[(size_t)(tile_m + row) * 512 + k0 + c0];
      *(short4*)&Xs[row * 72 + c0] =
          make_short4(f2b(xv.x), f2b(xv.y), f2b(xv.z), f2b(xv.w));
    }
    #pragma unroll
    for (int rep = 0; rep < 4; ++rep) {
      int e = rep * 256 + t;
      int row = e >> 3, c0 = (e & 7) * 8;
      *(int4*)&Wsh[row * 72 + c0] = *(const int4*)&Wt[(size_t)(tile_n + row) * 512 + k0 + c0];
    }
    __syncthreads();
    #pragma unroll
    for (int ks = 0; ks < 2; ++ks) {
      bf16x8 af[4], bfr[4];
      #pragma unroll
      for (int mt = 0; mt < 4; ++mt)
        af[mt] = *(bf16x8*)&Xs[(wm * 64 + mt * 16 + l15) * 72 + ks * 32 + quad * 8];
      #pragma unroll
      for (int nt = 0; nt < 4; ++nt)
        bfr[nt] = *(bf16x8*)&Wsh[(wn * 64 + nt * 16 + l15) * 72 + ks * 32 + quad * 8];
      #pragma unroll
      for (int mt = 0; mt < 4; ++mt)
        #pragma unroll
        for (int nt = 0; nt < 4; ++nt)
          acc[mt][nt] = MFMA16(af[mt], bfr[nt], acc[mt][nt]);
    }
  }

  const int col0 = tile_n + wn * 64;
  if (z < 2) {
    short* Y = (z == 0) ? qh : kh;
    #pragma unroll
    for (int nt = 0; nt < 4; ++nt) {
      int cc = col0 + nt * 16 + l15;
      int h = cc >> 6, d = cc & 63;
      #pragma unroll
      for (int mt = 0; mt < 4; ++mt) {
        #pragma unroll
        for (int r = 0; r < 4; ++r) {
          int row = tile_m + wm * 64 + mt * 16 + quad * 4 + r;
          int b = row >> 11, s = row & (S_ - 1);
          Y[(((size_t)(b * H_ + h)) * S_ + s) * 64 + d] = f2b(acc[mt][nt][r]);
        }
      }
    }
  } else {
    #pragma unroll
    for (int nt = 0; nt < 4; ++nt) {
      int cc = col0 + nt * 16 + l15;
      int h = cc >> 6, d = cc & 63;
      #pragma unroll
      for (int mt = 0; mt < 4; ++mt) {
        int row0 = tile_m + wm * 64 + mt * 16 + quad * 4;
        int b = row0 >> 11, s0 = row0 & (S_ - 1);
        short4 pk = make_short4(f2b(acc[mt][nt][0]), f2b(acc[mt][nt][1]),
                                f2b(acc[mt][nt][2]), f2b(acc[mt][nt][3]));
        *(short4*)&vt[(((size_t)(b * H_ + h)) * 64 + d) * S_ + s0] = pk;
      }
    }
  }
}

// ---------------------------------------------------------------------------
// Fused attention, MFMA bf16. QBLK=128, 512 threads (8 waves, 16 q-rows each).
// Double-buffered K/V in LDS -> ONE barrier per K-tile; each K/V tile serves
// 128 q-rows (half the staging + barrier cost of QBLK=64). Reg-staged
// prefetch; XOR-swizzled 128B-row tiles; non-temporal attn stores; mask row
// whole in LDS; Q frags direct from global; P tile wave-local.
// XCD-bijective block swizzle: 64 consecutive nl per XCD = 4 bh slices
// (~2 MB K+V) inside its private 4 MiB L2.
// ---------------------------------------------------------------------------
__global__ __launch_bounds__(512) void attn_mfma(
    const short* __restrict__ qh, const short* __restrict__ kh,
    const short* __restrict__ vt, const int* __restrict__ src_mask,
    float* __restrict__ attn_out, short* __restrict__ ohb)
{
  const int t = threadIdx.x;
  const int wave = t >> 6, lane = t & 63, quad = lane >> 4, l15 = lane & 15;

  // 512 blocks, 8 XCDs -> contiguous chunk of 64 nl per XCD.
  const int lin = blockIdx.y * 16 + blockIdx.x;
  const int nl  = (lin & 7) * 64 + (lin >> 3);
  const int bh = nl >> 4, b = bh >> 3, h = bh & 7;
  const int q0 = (nl & 15) * 128;

  __shared__ __align__(16) short KV[4][64 * 64];  // [0..1] K dbuf, [2..3] V dbuf
  __shared__ __align__(16) short Ps[8][16 * 72];  // per-wave P tile
  __shared__ __align__(16) int smAll[S_];         // full mask row for this b

  const short* __restrict__ khb = kh + (size_t)bh * S_ * 64;
  const short* __restrict__ vtb = vt + (size_t)bh * 64 * S_;

  // staging geometry: 512 threads -> one int4 each: row sr, 16B slot sc
  const int sr = t >> 3, sc = t & 7;
  const int wofs = sr * 128 + ((sc ^ (sr & 7)) << 4);           // swizzled write
  // read swizzle per lane: slot (ks*4+quad) ^ (row&7), row&7 == l15&7
  const int rofs0 = ((quad ^ (l15 & 7)) << 4);
  const int rofs1 = (((4 + quad) ^ (l15 & 7)) << 4);

  // Q fragments straight from global (row = wave*16+l15).
  const size_t qrow = (size_t)bh * S_ + q0 + wave * 16 + l15;
  const bf16x8 qf0 = *(const bf16x8*)&qh[qrow * 64 + quad * 8];
  const bf16x8 qf1 = *(const bf16x8*)&qh[qrow * 64 + 32 + quad * 8];

  // ---- prologue: mask row + K tile 0 ----
  int4 kreg, vreg;
  int4 mreg = *(const int4*)&src_mask[b * S_ + t * 4];
  kreg = *(const int4*)&khb[(size_t)sr * 64 + sc * 8];
  *(int4*)&smAll[t * 4] = mreg;
  *(int4*)((char*)KV[0] + wofs) = kreg;
  __syncthreads();

  int rloc[4], mqr[4], qir[4];
  #pragma unroll
  for (int r = 0; r < 4; ++r) {
    rloc[r] = wave * 16 + quad * 4 + r;
    qir[r] = q0 + rloc[r];
    mqr[r] = smAll[qir[r]];
  }

  // ---------------- Pass A: exp-sums ----------------
  float rs[4] = {0.f, 0.f, 0.f, 0.f};
  for (int step = 0; step < 32; ++step) {
    const int kt0 = step * 64;
    const int cur = step & 1;
    if (step < 31)
      kreg = *(const int4*)&khb[(size_t)(kt0 + 64 + sr) * 64 + sc * 8];
    const char* Kc = (const char*)KV[cur];
    #pragma unroll
    for (int nt = 0; nt < 4; ++nt) {
      bf16x8 kf0 = *(const bf16x8*)(Kc + (nt * 16 + l15) * 128 + rofs0);
      bf16x8 kf1 = *(const bf16x8*)(Kc + (nt * 16 + l15) * 128 + rofs1);
      f32x4 c = (f32x4){0.f, 0.f, 0.f, 0.f};
      c = MFMA16(qf0, kf0, c);
      c = MFMA16(qf1, kf1, c);
      int kj = kt0 + nt * 16 + l15;
      int mk = smAll[kj];
      #pragma unroll
      for (int r = 0; r < 4; ++r) {
        float ss = c[r] * 0.125f;
        bool keep = (mqr[r] & mk) || (qir[r] == kj);
        ss = keep ? ss : NEG_FILL;
        rs[r] += __expf(ss);
      }
    }
    if (step < 31)
      *(int4*)((char*)KV[cur ^ 1] + wofs) = kreg;
    __syncthreads();
  }
  // reduce across the 16 lanes holding one row's columns; keep inverse
  #pragma unroll
  for (int r = 0; r < 4; ++r) {
    float vsum = rs[r];
    vsum += __shfl_xor(vsum, 1);
    vsum += __shfl_xor(vsum, 2);
    vsum += __shfl_xor(vsum, 4);
    vsum += __shfl_xor(vsum, 8);
    rs[r] = 1.f / vsum;
  }

  // ---------------- Pass B: attn write + PV ----------------
  f32x4 oacc[4];
  #pragma unroll
  for (int dt = 0; dt < 4; ++dt) oacc[dt] = (f32x4){0.f, 0.f, 0.f, 0.f};

  float* __restrict__ arow[4];
  #pragma unroll
  for (int r = 0; r < 4; ++r)
    arow[r] = attn_out + ((size_t)bh * S_ + q0 + rloc[r]) * S_;

  short* __restrict__ ps = Ps[wave];

  // prologue: K tile 0 -> KV[0], V tile 0 -> KV[2]  (pass A ended on barrier)
  kreg = *(const int4*)&khb[(size_t)sr * 64 + sc * 8];
  vreg = *(const int4*)&vtb[(size_t)sr * S_ + sc * 8];
  *(int4*)((char*)KV[0] + wofs) = kreg;
  *(int4*)((char*)KV[2] + wofs) = vreg;
  __syncthreads();

  for (int step = 0; step < 32; ++step) {
    const int kt0 = step * 64;
    const int cur = step & 1;
    if (step < 31) {
      kreg = *(const int4*)&khb[(size_t)(kt0 + 64 + sr) * 64 + sc * 8];
      vreg = *(const int4*)&vtb[(size_t)sr * S_ + kt0 + 64 + sc * 8];
    }
    const char* Kc = (const char*)KV[cur];
    const char* Vc = (const char*)KV[2 + cur];
    #pragma unroll
    for (int nt = 0; nt < 4; ++nt) {
      bf16x8 kf0 = *(const bf16x8*)(Kc + (nt * 16 + l15) * 128 + rofs0);
      bf16x8 kf1 = *(const bf16x8*)(Kc + (nt * 16 + l15) * 128 + rofs1);
      f32x4 c = (f32x4){0.f, 0.f, 0.f, 0.f};
      c = MFMA16(qf0, kf0, c);
      c = MFMA16(qf1, kf1, c);
      int kj = kt0 + nt * 16 + l15;
      int mk = smAll[kj];
      #pragma unroll
      for (int r = 0; r < 4; ++r) {
        float ss = c[r] * 0.125f;
        bool keep = (mqr[r] & mk) || (qir[r] == kj);
        ss = keep ? ss : NEG_FILL;
        float p = __expf(ss) * rs[r];
        __builtin_nontemporal_store(p, &arow[r][kj]);
        ps[(quad * 4 + r) * 72 + nt * 16 + l15] = f2b(p);
      }
    }
    // wave-local P transpose readback (same wave wrote these rows)
    bf16x8 pf0 = *(bf16x8*)&ps[l15 * 72 + quad * 8];
    bf16x8 pf1 = *(bf16x8*)&ps[l15 * 72 + 32 + quad * 8];
    #pragma unroll
    for (int dt = 0; dt < 4; ++dt) {
      bf16x8 vf0 = *(const bf16x8*)(Vc + (dt * 16 + l15) * 128 + rofs0);
      bf16x8 vf1 = *(const bf16x8*)(Vc + (dt * 16 + l15) * 128 + rofs1);
      oacc[dt] = MFMA16(pf0, vf0, oacc[dt]);
      oacc[dt] = MFMA16(pf1, vf1, oacc[dt]);
    }
    if (step < 31) {
      *(int4*)((char*)KV[cur ^ 1] + wofs) = kreg;
      *(int4*)((char*)KV[2 + (cur ^ 1)] + wofs) = vreg;
    }
    __syncthreads();
  }

  // ---- write O tile (bf16) ----
  #pragma unroll
  for (int dt = 0; dt < 4; ++dt) {
    int d = h * 64 + dt * 16 + l15;
    #pragma unroll
    for (int r = 0; r < 4; ++r)
      ohb[((size_t)b * S_ + q0 + rloc[r]) * 512 + d] = f2b(oacc[dt][r]);
  }
}

// ---------------------------------------------------------------------------
// out = ohb @ Wo + residual(q), MFMA bf16, fp32 out (round-0 proven structure).
// ---------------------------------------------------------------------------
__global__ __launch_bounds__(256) void out_mfma(
    const short* __restrict__ ohb, const short* __restrict__ Wot,
    const float* __restrict__ resid, float* __restrict__ out)
{
  __shared__ short Xs[64 * 72];
  __shared__ short Wsh[64 * 72];

  const int t = threadIdx.x;
  const int wave = t >> 6, lane = t & 63, quad = lane >> 4, l15 = lane & 15;
  const int tile_n = blockIdx.x * 64;
  const int tile_m = blockIdx.y * 64;

  f32x4 acc[4];
  #pragma unroll
  for (int nt = 0; nt < 4; ++nt) acc[nt] = (f32x4){0.f, 0.f, 0.f, 0.f};

  for (int k0 = 0; k0 < 512; k0 += 64) {
    __syncthreads();
    #pragma unroll
    for (int rep = 0; rep < 2; ++rep) {
      int e = rep * 256 + t;
      int row = e >> 3, c0 = (e & 7) * 8;
      *(int4*)&Xs[row * 72 + c0] = *(const int4*)&ohb[(size_t)(tile_m + row) * 512 + k0 + c0];
      *(int4*)&Wsh[row * 72 + c0] = *(const int4*)&Wot[(size_t)(tile_n + row) * 512 + k0 + c0];
    }
    __syncthreads();
    #pragma unroll
    for (int ks = 0; ks < 2; ++ks) {
      bf16x8 af = *(bf16x8*)&Xs[(wave * 16 + l15) * 72 + ks * 32 + quad * 8];
      #pragma unroll
      for (int nt = 0; nt < 4; ++nt) {
        bf16x8 bfr = *(bf16x8*)&Wsh[(nt * 16 + l15) * 72 + ks * 32 + quad * 8];
        acc[nt] = MFMA16(af, bfr, acc[nt]);
      }
    }
  }

  #pragma unroll
  for (int nt = 0; nt < 4; ++nt) {
    int c = tile_n + nt * 16 + l15;
    #pragma unroll
    for (int r = 0; r < 4; ++r) {
      size_t row = tile_m + wave * 16 + quad * 4 + r;
      out[row * 512 + c] = acc[nt][r] + resid[row * 512 + c];
    }
  }
}

// ---------------------------------------------------------------------------
// LayerNorm over last dim (512), one wave per row, in place.
// ---------------------------------------------------------------------------
__global__ __launch_bounds__(256) void ln_kernel(
    float* __restrict__ io, const float* __restrict__ gamma, const float* __restrict__ beta)
{
  const int wid  = threadIdx.x >> 6;
  const int lane = threadIdx.x & 63;
  const size_t row = (size_t)blockIdx.x * 4 + wid;
  const size_t base = row * 512 + lane * 8;

  float4 x0 = *(const float4*)&io[base];
  float4 x1 = *(const float4*)&io[base + 4];
  float xs[8] = {x0.x, x0.y, x0.z, x0.w, x1.x, x1.y, x1.z, x1.w};

  float s = 0.f, s2 = 0.f;
  #pragma unroll
  for (int i = 0; i < 8; ++i) { s += xs[i]; s2 = fmaf(xs[i], xs[i], s2); }
  #pragma unroll
  for (int m = 1; m < 64; m <<= 1) {
    s  += __shfl_xor(s, m);
    s2 += __shfl_xor(s2, m);
  }
  float mu  = s * (1.f / 512.f);
  float var = s2 * (1.f / 512.f) - mu * mu;
  float rsq = rsqrtf(var + 1e-6f);

  float4 g0 = *(const float4*)&gamma[lane * 8];
  float4 g1 = *(const float4*)&gamma[lane * 8 + 4];
  float4 b0 = *(const float4*)&beta[lane * 8];
  float4 b1 = *(const float4*)&beta[lane * 8 + 4];
  float gs[8] = {g0.x, g0.y, g0.z, g0.w, g1.x, g1.y, g1.z, g1.w};
  float bs[8] = {b0.x, b0.y, b0.z, b0.w, b1.x, b1.y, b1.z, b1.w};

  float ys[8];
  #pragma unroll
  for (int i = 0; i < 8; ++i) ys[i] = (xs[i] - mu) * rsq * gs[i] + bs[i];
  *(float4*)&io[base]     = make_float4(ys[0], ys[1], ys[2], ys[3]);
  *(float4*)&io[base + 4] = make_float4(ys[4], ys[5], ys[6], ys[7]);
}

// ---------------------------------------------------------------------------
extern "C" void kernel_launch(void* const* d_in, const int* in_sizes, int n_in,
                              void* d_out, int out_size, void* d_ws, size_t ws_size,
                              hipStream_t stream)
{
  const float* q     = (const float*)d_in[0];
  const float* k     = (const float*)d_in[1];
  const float* v     = (const float*)d_in[2];
  const int*  smask  = (const int*)d_in[3];
  const float* Wq    = (const float*)d_in[4];
  const float* Wk    = (const float*)d_in[5];
  const float* Wv    = (const float*)d_in[6];
  const float* Wo    = (const float*)d_in[7];
  const float* gamma = (const float*)d_in[8];
  const float* beta  = (const float*)d_in[9];

  float* out  = (float*)d_out;
  float* attn = out + (size_t)B_ * S_ * D_;

  short* wsS = (short*)d_ws;
  short* qh  = wsS;                    // [32 bh][2048][64]
  short* kh  = qh + 4194304;
  short* vt  = kh + 4194304;           // [32 bh][64][2048]
  short* ohb = vt + 4194304;           // [8192][512]
  short* Wqt = ohb + 4194304;          // [512][512] each
  short* Wkt = Wqt + 262144;
  short* Wvt = Wkt + 262144;
  short* Wot = Wvt + 262144;

  prep_wt<<<dim3(8, 8, 4), 256, 0, stream>>>(Wq, Wk, Wv, Wo, Wqt, Wkt, Wvt, Wot);
  qkv_mfma<<<dim3(4, 64, 3), 256, 0, stream>>>(q, k, v, Wqt, Wkt, Wvt, qh, kh, vt);
  attn_mfma<<<dim3(16, 32), 512, 0, stream>>>(qh, kh, vt, smask, attn, ohb);
  out_mfma<<<dim3(8, 128), 256, 0, stream>>>(ohb, Wot, q, out);
  ln_kernel<<<2048, 256, 0, stream>>>(out, gamma, beta);
}

// Round 6
// 723.422 us; speedup vs baseline: 1.0299x; 1.0299x over previous
//
#include <hip/hip_runtime.h>
#include <math.h>

#define B_ 4
#define S_ 2048
#define D_ 512
#define H_ 8
#define NEG_FILL (-1e-9f)

typedef __attribute__((ext_vector_type(8))) short bf16x8;
typedef __attribute__((ext_vector_type(4))) float f32x4;

#define MFMA16(A, Bm, C) __builtin_amdgcn_mfma_f32_16x16x32_bf16((A), (Bm), (C), 0, 0, 0)

__device__ __forceinline__ short f2b(float f) {
  union { float f; unsigned u; } x;
  x.f = f;
  unsigned r = x.u + 0x7fffu + ((x.u >> 16) & 1u);
  return (short)(r >> 16);
}

// ---------------------------------------------------------------------------
// prep: W[512x512] fp32 (k-major) -> Wt[n][k] bf16 (transposed), z picks matrix
// ---------------------------------------------------------------------------
__global__ __launch_bounds__(256) void prep_wt(
    const float* __restrict__ Wq, const float* __restrict__ Wk,
    const float* __restrict__ Wv, const float* __restrict__ Wo,
    short* __restrict__ Wqt, short* __restrict__ Wkt,
    short* __restrict__ Wvt, short* __restrict__ Wot)
{
  const float* W; short* Wt;
  switch (blockIdx.z) {
    case 0: W = Wq; Wt = Wqt; break;
    case 1: W = Wk; Wt = Wkt; break;
    case 2: W = Wv; Wt = Wvt; break;
    default: W = Wo; Wt = Wot; break;
  }
  __shared__ float Ws[64 * 68];
  const int t = threadIdx.x;
  const int n0 = blockIdx.x * 64, k0 = blockIdx.y * 64;

  #pragma unroll
  for (int rep = 0; rep < 4; ++rep) {
    int e4 = rep * 256 + t;           // float4 units
    int r = e4 >> 4, c0 = (e4 & 15) * 4;
    *(float4*)&Ws[r * 68 + c0] = *(const float4*)&W[(size_t)(k0 + r) * 512 + n0 + c0];
  }
  __syncthreads();

  int rn = t >> 2;                    // out row (n)
  int kb = (t & 3) * 16;              // out col base (k)
  union { short s[8]; int4 v; } pk;
  #pragma unroll
  for (int half = 0; half < 2; ++half) {
    #pragma unroll
    for (int i = 0; i < 8; ++i)
      pk.s[i] = f2b(Ws[(kb + half * 8 + i) * 68 + rn]);
    *(int4*)&Wt[(size_t)(n0 + rn) * 512 + k0 + kb + half * 8] = pk.v;
  }
}

// ---------------------------------------------------------------------------
// x2b: convert q/k/v fp32 -> bf16 ONCE (removes 8x-redundant f2b from qkv).
// Outputs live in the (not-yet-written) attn region of d_out -- no extra
// workspace beyond the round-3-proven footprint.
// ---------------------------------------------------------------------------
__global__ __launch_bounds__(256) void x2b(
    const float* __restrict__ q, const float* __restrict__ k, const float* __restrict__ v,
    short* __restrict__ qb, short* __restrict__ kb, short* __restrict__ vb)
{
  const float* X = (blockIdx.y == 0) ? q : (blockIdx.y == 1) ? k : v;
  short* Y = (blockIdx.y == 0) ? qb : (blockIdx.y == 1) ? kb : vb;
  const size_t i = ((size_t)blockIdx.x * 256 + threadIdx.x) * 8;
  float4 a = *(const float4*)&X[i];
  float4 b = *(const float4*)&X[i + 4];
  union { short s[8]; int4 v; } pk;
  pk.s[0] = f2b(a.x); pk.s[1] = f2b(a.y); pk.s[2] = f2b(a.z); pk.s[3] = f2b(a.w);
  pk.s[4] = f2b(b.x); pk.s[5] = f2b(b.y); pk.s[6] = f2b(b.z); pk.s[7] = f2b(b.w);
  *(int4*)&Y[i] = pk.v;
}

// ---------------------------------------------------------------------------
// QKV projection, MFMA bf16. Xb[8192x512] bf16 (pre-converted), Wt[n][k] bf16.
// Staging is pure int4 copies (no f2b in the inner loop).
// z=0 -> qh[bh][s][64], z=1 -> kh[bh][s][64], z=2 -> vt[bh][d][2048]
// ---------------------------------------------------------------------------
__global__ __launch_bounds__(256) void qkv_mfma(
    const short* __restrict__ qb, const short* __restrict__ kb, const short* __restrict__ vb,
    const short* __restrict__ Wqt, const short* __restrict__ Wkt, const short* __restrict__ Wvt,
    short* __restrict__ qh, short* __restrict__ kh, short* __restrict__ vt)
{
  const int z = blockIdx.z;
  const short* Xb = (z == 0) ? qb : (z == 1) ? kb : vb;
  const short* Wt = (z == 0) ? Wqt : (z == 1) ? Wkt : Wvt;

  __shared__ short Xs[64 * 72];
  __shared__ short Wsh[64 * 72];

  const int t = threadIdx.x;
  const int wave = t >> 6, lane = t & 63, quad = lane >> 4, l15 = lane & 15;
  const int tile_n = blockIdx.x * 64;
  const int tile_m = blockIdx.y * 64;

  f32x4 acc[4];
  #pragma unroll
  for (int nt = 0; nt < 4; ++nt) acc[nt] = (f32x4){0.f, 0.f, 0.f, 0.f};

  for (int k0 = 0; k0 < 512; k0 += 64) {
    __syncthreads();
    #pragma unroll
    for (int rep = 0; rep < 2; ++rep) {
      int e = rep * 256 + t;
      int row = e >> 3, c0 = (e & 7) * 8;
      *(int4*)&Xs[row * 72 + c0] = *(const int4*)&Xb[(size_t)(tile_m + row) * 512 + k0 + c0];
      *(int4*)&Wsh[row * 72 + c0] = *(const int4*)&Wt[(size_t)(tile_n + row) * 512 + k0 + c0];
    }
    __syncthreads();
    #pragma unroll
    for (int ks = 0; ks < 2; ++ks) {
      bf16x8 af = *(bf16x8*)&Xs[(wave * 16 + l15) * 72 + ks * 32 + quad * 8];
      #pragma unroll
      for (int nt = 0; nt < 4; ++nt) {
        bf16x8 bfr = *(bf16x8*)&Wsh[(nt * 16 + l15) * 72 + ks * 32 + quad * 8];
        acc[nt] = MFMA16(af, bfr, acc[nt]);
      }
    }
  }

  const int h = tile_n >> 6;
  if (z < 2) {
    short* Y = (z == 0) ? qh : kh;
    #pragma unroll
    for (int nt = 0; nt < 4; ++nt) {
      int d = nt * 16 + l15;
      #pragma unroll
      for (int r = 0; r < 4; ++r) {
        int row = tile_m + wave * 16 + quad * 4 + r;
        int b = row >> 11, s = row & (S_ - 1);
        Y[(((size_t)(b * H_ + h)) * S_ + s) * 64 + d] = f2b(acc[nt][r]);
      }
    }
  } else {
    int row0 = tile_m + wave * 16 + quad * 4;
    int b = row0 >> 11, s0 = row0 & (S_ - 1);
    #pragma unroll
    for (int nt = 0; nt < 4; ++nt) {
      int d = nt * 16 + l15;
      short4 pk = make_short4(f2b(acc[nt][0]), f2b(acc[nt][1]),
                              f2b(acc[nt][2]), f2b(acc[nt][3]));
      *(short4*)&vt[(((size_t)(b * H_ + h)) * 64 + d) * S_ + s0] = pk;
    }
  }
}

// ---------------------------------------------------------------------------
// Fused attention, MFMA bf16 (round-3 proven). Double-buffered K/V in LDS ->
// ONE barrier per K-tile; reg-staged prefetch; XOR-swizzled 128B-row tiles;
// non-temporal attn stores; mask row whole in LDS; Q frags direct from
// global; P tile wave-local. XCD-bijective block swizzle.
// ---------------------------------------------------------------------------
__global__ __launch_bounds__(256) void attn_mfma(
    const short* __restrict__ qh, const short* __restrict__ kh,
    const short* __restrict__ vt, const int* __restrict__ src_mask,
    float* __restrict__ attn_out, short* __restrict__ ohb)
{
  const int t = threadIdx.x;
  const int wave = t >> 6, lane = t & 63, quad = lane >> 4, l15 = lane & 15;

  // 1024 blocks, 8 XCDs -> contiguous chunk of 128 nl per XCD.
  const int lin = blockIdx.y * 32 + blockIdx.x;
  const int nl  = (lin & 7) * 128 + (lin >> 3);
  const int bh = nl >> 5, b = bh >> 3, h = bh & 7;
  const int q0 = (nl & 31) * 64;

  __shared__ __align__(16) short KV[4][64 * 64];  // [0..1] K dbuf, [2..3] V dbuf
  __shared__ __align__(16) short Ps[4][16 * 72];  // per-wave P tile
  __shared__ __align__(16) int smAll[S_];         // full mask row for this b

  const short* __restrict__ khb = kh + (size_t)bh * S_ * 64;
  const short* __restrict__ vtb = vt + (size_t)bh * 64 * S_;

  // staging geometry: thread t -> rows sr, sr+32; 16B slot sc within 128B row
  const int sr = t >> 3, sc = t & 7;
  const int wofs0 = sr * 128 + ((sc ^ (sr & 7)) << 4);          // swizzled write
  const int wofs1 = (sr + 32) * 128 + ((sc ^ (sr & 7)) << 4);
  // read swizzle per lane: slot (ks*4+quad) ^ (row&7), row&7 == l15&7
  const int rofs0 = ((quad ^ (l15 & 7)) << 4);
  const int rofs1 = (((4 + quad) ^ (l15 & 7)) << 4);

  // Q fragments straight from global (row = wave*16+l15).
  const size_t qrow = (size_t)bh * S_ + q0 + wave * 16 + l15;
  const bf16x8 qf0 = *(const bf16x8*)&qh[qrow * 64 + quad * 8];
  const bf16x8 qf1 = *(const bf16x8*)&qh[qrow * 64 + 32 + quad * 8];

  // ---- prologue: mask row + K tile 0 ----
  int4 kreg0, kreg1, vreg0, vreg1;
  int4 mreg0 = *(const int4*)&src_mask[b * S_ + t * 4];
  int4 mreg1 = *(const int4*)&src_mask[b * S_ + (256 + t) * 4];
  kreg0 = *(const int4*)&khb[(size_t)sr * 64 + sc * 8];
  kreg1 = *(const int4*)&khb[(size_t)(sr + 32) * 64 + sc * 8];
  *(int4*)&smAll[t * 4] = mreg0;
  *(int4*)&smAll[(256 + t) * 4] = mreg1;
  *(int4*)((char*)KV[0] + wofs0) = kreg0;
  *(int4*)((char*)KV[0] + wofs1) = kreg1;
  __syncthreads();

  int rloc[4], mqr[4], qir[4];
  #pragma unroll
  for (int r = 0; r < 4; ++r) {
    rloc[r] = wave * 16 + quad * 4 + r;
    qir[r] = q0 + rloc[r];
    mqr[r] = smAll[qir[r]];
  }

  // ---------------- Pass A: exp-sums ----------------
  float rs[4] = {0.f, 0.f, 0.f, 0.f};
  for (int step = 0; step < 32; ++step) {
    const int kt0 = step * 64;
    const int cur = step & 1;
    if (step < 31) {
      kreg0 = *(const int4*)&khb[(size_t)(kt0 + 64 + sr) * 64 + sc * 8];
      kreg1 = *(const int4*)&khb[(size_t)(kt0 + 64 + sr + 32) * 64 + sc * 8];
    }
    const char* Kc = (const char*)KV[cur];
    #pragma unroll
    for (int nt = 0; nt < 4; ++nt) {
      bf16x8 kf0 = *(const bf16x8*)(Kc + (nt * 16 + l15) * 128 + rofs0);
      bf16x8 kf1 = *(const bf16x8*)(Kc + (nt * 16 + l15) * 128 + rofs1);
      f32x4 c = (f32x4){0.f, 0.f, 0.f, 0.f};
      c = MFMA16(qf0, kf0, c);
      c = MFMA16(qf1, kf1, c);
      int kj = kt0 + nt * 16 + l15;
      int mk = smAll[kj];
      #pragma unroll
      for (int r = 0; r < 4; ++r) {
        float ss = c[r] * 0.125f;
        bool keep = (mqr[r] & mk) || (qir[r] == kj);
        ss = keep ? ss : NEG_FILL;
        rs[r] += __expf(ss);
      }
    }
    if (step < 31) {
      *(int4*)((char*)KV[cur ^ 1] + wofs0) = kreg0;
      *(int4*)((char*)KV[cur ^ 1] + wofs1) = kreg1;
    }
    __syncthreads();
  }
  // reduce across the 16 lanes holding one row's columns; keep inverse
  #pragma unroll
  for (int r = 0; r < 4; ++r) {
    float vsum = rs[r];
    vsum += __shfl_xor(vsum, 1);
    vsum += __shfl_xor(vsum, 2);
    vsum += __shfl_xor(vsum, 4);
    vsum += __shfl_xor(vsum, 8);
    rs[r] = 1.f / vsum;
  }

  // ---------------- Pass B: attn write + PV ----------------
  f32x4 oacc[4];
  #pragma unroll
  for (int dt = 0; dt < 4; ++dt) oacc[dt] = (f32x4){0.f, 0.f, 0.f, 0.f};

  float* __restrict__ arow[4];
  #pragma unroll
  for (int r = 0; r < 4; ++r)
    arow[r] = attn_out + ((size_t)bh * S_ + q0 + rloc[r]) * S_;

  short* __restrict__ ps = Ps[wave];

  // prologue: K tile 0 -> KV[0], V tile 0 -> KV[2]  (pass A ended on barrier)
  kreg0 = *(const int4*)&khb[(size_t)sr * 64 + sc * 8];
  kreg1 = *(const int4*)&khb[(size_t)(sr + 32) * 64 + sc * 8];
  vreg0 = *(const int4*)&vtb[(size_t)sr * S_ + sc * 8];
  vreg1 = *(const int4*)&vtb[(size_t)(sr + 32) * S_ + sc * 8];
  *(int4*)((char*)KV[0] + wofs0) = kreg0;
  *(int4*)((char*)KV[0] + wofs1) = kreg1;
  *(int4*)((char*)KV[2] + wofs0) = vreg0;
  *(int4*)((char*)KV[2] + wofs1) = vreg1;
  __syncthreads();

  for (int step = 0; step < 32; ++step) {
    const int kt0 = step * 64;
    const int cur = step & 1;
    if (step < 31) {
      kreg0 = *(const int4*)&khb[(size_t)(kt0 + 64 + sr) * 64 + sc * 8];
      kreg1 = *(const int4*)&khb[(size_t)(kt0 + 64 + sr + 32) * 64 + sc * 8];
      vreg0 = *(const int4*)&vtb[(size_t)sr * S_ + kt0 + 64 + sc * 8];
      vreg1 = *(const int4*)&vtb[(size_t)(sr + 32) * S_ + kt0 + 64 + sc * 8];
    }
    const char* Kc = (const char*)KV[cur];
    const char* Vc = (const char*)KV[2 + cur];
    #pragma unroll
    for (int nt = 0; nt < 4; ++nt) {
      bf16x8 kf0 = *(const bf16x8*)(Kc + (nt * 16 + l15) * 128 + rofs0);
      bf16x8 kf1 = *(const bf16x8*)(Kc + (nt * 16 + l15) * 128 + rofs1);
      f32x4 c = (f32x4){0.f, 0.f, 0.f, 0.f};
      c = MFMA16(qf0, kf0, c);
      c = MFMA16(qf1, kf1, c);
      int kj = kt0 + nt * 16 + l15;
      int mk = smAll[kj];
      #pragma unroll
      for (int r = 0; r < 4; ++r) {
        float ss = c[r] * 0.125f;
        bool keep = (mqr[r] & mk) || (qir[r] == kj);
        ss = keep ? ss : NEG_FILL;
        float p = __expf(ss) * rs[r];
        __builtin_nontemporal_store(p, &arow[r][kj]);
        ps[(quad * 4 + r) * 72 + nt * 16 + l15] = f2b(p);
      }
    }
    // wave-local P transpose readback (same wave wrote these rows)
    bf16x8 pf0 = *(bf16x8*)&ps[l15 * 72 + quad * 8];
    bf16x8 pf1 = *(bf16x8*)&ps[l15 * 72 + 32 + quad * 8];
    #pragma unroll
    for (int dt = 0; dt < 4; ++dt) {
      bf16x8 vf0 = *(const bf16x8*)(Vc + (dt * 16 + l15) * 128 + rofs0);
      bf16x8 vf1 = *(const bf16x8*)(Vc + (dt * 16 + l15) * 128 + rofs1);
      oacc[dt] = MFMA16(pf0, vf0, oacc[dt]);
      oacc[dt] = MFMA16(pf1, vf1, oacc[dt]);
    }
    if (step < 31) {
      *(int4*)((char*)KV[cur ^ 1] + wofs0) = kreg0;
      *(int4*)((char*)KV[cur ^ 1] + wofs1) = kreg1;
      *(int4*)((char*)KV[2 + (cur ^ 1)] + wofs0) = vreg0;
      *(int4*)((char*)KV[2 + (cur ^ 1)] + wofs1) = vreg1;
    }
    __syncthreads();
  }

  // ---- write O tile (bf16) ----
  #pragma unroll
  for (int dt = 0; dt < 4; ++dt) {
    int d = h * 64 + dt * 16 + l15;
    #pragma unroll
    for (int r = 0; r < 4; ++r)
      ohb[((size_t)b * S_ + q0 + rloc[r]) * 512 + d] = f2b(oacc[dt][r]);
  }
}

// ---------------------------------------------------------------------------
// out = ohb @ Wo + residual(q), MFMA bf16, fp32 out (round-0 proven structure).
// ---------------------------------------------------------------------------
__global__ __launch_bounds__(256) void out_mfma(
    const short* __restrict__ ohb, const short* __restrict__ Wot,
    const float* __restrict__ resid, float* __restrict__ out)
{
  __shared__ short Xs[64 * 72];
  __shared__ short Wsh[64 * 72];

  const int t = threadIdx.x;
  const int wave = t >> 6, lane = t & 63, quad = lane >> 4, l15 = lane & 15;
  const int tile_n = blockIdx.x * 64;
  const int tile_m = blockIdx.y * 64;

  f32x4 acc[4];
  #pragma unroll
  for (int nt = 0; nt < 4; ++nt) acc[nt] = (f32x4){0.f, 0.f, 0.f, 0.f};

  for (int k0 = 0; k0 < 512; k0 += 64) {
    __syncthreads();
    #pragma unroll
    for (int rep = 0; rep < 2; ++rep) {
      int e = rep * 256 + t;
      int row = e >> 3, c0 = (e & 7) * 8;
      *(int4*)&Xs[row * 72 + c0] = *(const int4*)&ohb[(size_t)(tile_m + row) * 512 + k0 + c0];
      *(int4*)&Wsh[row * 72 + c0] = *(const int4*)&Wot[(size_t)(tile_n + row) * 512 + k0 + c0];
    }
    __syncthreads();
    #pragma unroll
    for (int ks = 0; ks < 2; ++ks) {
      bf16x8 af = *(bf16x8*)&Xs[(wave * 16 + l15) * 72 + ks * 32 + quad * 8];
      #pragma unroll
      for (int nt = 0; nt < 4; ++nt) {
        bf16x8 bfr = *(bf16x8*)&Wsh[(nt * 16 + l15) * 72 + ks * 32 + quad * 8];
        acc[nt] = MFMA16(af, bfr, acc[nt]);
      }
    }
  }

  #pragma unroll
  for (int nt = 0; nt < 4; ++nt) {
    int c = tile_n + nt * 16 + l15;
    #pragma unroll
    for (int r = 0; r < 4; ++r) {
      size_t row = tile_m + wave * 16 + quad * 4 + r;
      out[row * 512 + c] = acc[nt][r] + resid[row * 512 + c];
    }
  }
}

// ---------------------------------------------------------------------------
// LayerNorm over last dim (512), one wave per row, in place.
// ---------------------------------------------------------------------------
__global__ __launch_bounds__(256) void ln_kernel(
    float* __restrict__ io, const float* __restrict__ gamma, const float* __restrict__ beta)
{
  const int wid  = threadIdx.x >> 6;
  const int lane = threadIdx.x & 63;
  const size_t row = (size_t)blockIdx.x * 4 + wid;
  const size_t base = row * 512 + lane * 8;

  float4 x0 = *(const float4*)&io[base];
  float4 x1 = *(const float4*)&io[base + 4];
  float xs[8] = {x0.x, x0.y, x0.z, x0.w, x1.x, x1.y, x1.z, x1.w};

  float s = 0.f, s2 = 0.f;
  #pragma unroll
  for (int i = 0; i < 8; ++i) { s += xs[i]; s2 = fmaf(xs[i], xs[i], s2); }
  #pragma unroll
  for (int m = 1; m < 64; m <<= 1) {
    s  += __shfl_xor(s, m);
    s2 += __shfl_xor(s2, m);
  }
  float mu  = s * (1.f / 512.f);
  float var = s2 * (1.f / 512.f) - mu * mu;
  float rsq = rsqrtf(var + 1e-6f);

  float4 g0 = *(const float4*)&gamma[lane * 8];
  float4 g1 = *(const float4*)&gamma[lane * 8 + 4];
  float4 b0 = *(const float4*)&beta[lane * 8];
  float4 b1 = *(const float4*)&beta[lane * 8 + 4];
  float gs[8] = {g0.x, g0.y, g0.z, g0.w, g1.x, g1.y, g1.z, g1.w};
  float bs[8] = {b0.x, b0.y, b0.z, b0.w, b1.x, b1.y, b1.z, b1.w};

  float ys[8];
  #pragma unroll
  for (int i = 0; i < 8; ++i) ys[i] = (xs[i] - mu) * rsq * gs[i] + bs[i];
  *(float4*)&io[base]     = make_float4(ys[0], ys[1], ys[2], ys[3]);
  *(float4*)&io[base + 4] = make_float4(ys[4], ys[5], ys[6], ys[7]);
}

// ---------------------------------------------------------------------------
extern "C" void kernel_launch(void* const* d_in, const int* in_sizes, int n_in,
                              void* d_out, int out_size, void* d_ws, size_t ws_size,
                              hipStream_t stream)
{
  const float* q     = (const float*)d_in[0];
  const float* k     = (const float*)d_in[1];
  const float* v     = (const float*)d_in[2];
  const int*  smask  = (const int*)d_in[3];
  const float* Wq    = (const float*)d_in[4];
  const float* Wk    = (const float*)d_in[5];
  const float* Wv    = (const float*)d_in[6];
  const float* Wo    = (const float*)d_in[7];
  const float* gamma = (const float*)d_in[8];
  const float* beta  = (const float*)d_in[9];

  float* out  = (float*)d_out;
  float* attn = out + (size_t)B_ * S_ * D_;

  short* wsS = (short*)d_ws;
  short* qh  = wsS;                    // [32 bh][2048][64]
  short* kh  = qh + 4194304;
  short* vt  = kh + 4194304;           // [32 bh][64][2048]
  short* ohb = vt + 4194304;           // [8192][512]
  short* Wqt = ohb + 4194304;          // [512][512] each
  short* Wkt = Wqt + 262144;
  short* Wvt = Wkt + 262144;
  short* Wot = Wvt + 262144;

  // Scratch bf16 copies of q/k/v live in the attn output region (536 MB),
  // which attn_mfma overwrites only AFTER qkv_mfma has consumed these.
  // Keeps d_ws usage identical to the round-3-proven footprint.
  short* qb = (short*)attn;            // [8192][512] bf16 each (24 MB total)
  short* kb = qb + 4194304;
  short* vb = kb + 4194304;

  prep_wt<<<dim3(8, 8, 4), 256, 0, stream>>>(Wq, Wk, Wv, Wo, Wqt, Wkt, Wvt, Wot);
  x2b<<<dim3(2048, 3), 256, 0, stream>>>(q, k, v, qb, kb, vb);
  qkv_mfma<<<dim3(8, 128, 3), 256, 0, stream>>>(qb, kb, vb, Wqt, Wkt, Wvt, qh, kh, vt);
  attn_mfma<<<dim3(32, 32), 256, 0, stream>>>(qh, kh, vt, smask, attn, ohb);
  out_mfma<<<dim3(8, 128), 256, 0, stream>>>(ohb, Wot, q, out);
  ln_kernel<<<2048, 256, 0, stream>>>(out, gamma, beta);
}